// Round 7
// baseline (275.692 us; speedup 1.0000x reference)
//
#include <hip/hip_runtime.h>
#include <stdint.h>

// Problem: N=131072, D=128, W=16, R=5
//   logit[n,r] = e1[n]^T C_r e2[n],  C_r = sum_w weight[w,r] * M_w
//   out[0] = -mean(log_softmax(logit)[n, rels[n]]),  out[1..N] = expected rating
//
// R7: pure bf16 (1-term). Error analysis: dropped residual terms are two
// 128-term CLT sums -> logit err std ~0.11, pred absmax ~0.3-1.0 vs
// threshold 3.12. Register budget ~105 -> fits __launch_bounds__(256,4)
// (128-reg cap) WITHOUT spill (R6's 3-term spilled at this cap).
// SA=144 retained (measured 0 bank conflicts).

#define NTOT 131072
#define DDIM 128
#define WBAS 16
#define RCLS 5
#define BN   64
#define SA   144     // LDS row stride (bf16); 288 B rows: conflict-free b128 (R6: 0)

typedef __attribute__((ext_vector_type(8))) short bf16x8;
typedef __attribute__((ext_vector_type(4))) float f32x4;

__device__ __forceinline__ unsigned short f2bf(float x) {
    union { float f; unsigned u; } v; v.f = x;
    unsigned u = v.u + 0x7FFFu + ((v.u >> 16) & 1u);
    return (unsigned short)(u >> 16);
}

// ---- prep: coalesced read (lanes along e), LDS transpose, bf16 hi only ----
// grid = 80 blocks: r = bx>>4 (5), d-band d0 = (bx&15)*8 (16)
__global__ __launch_bounds__(256) void prep_kernel(
    const float* __restrict__ rel_embeds,    // [W][d][e]
    const float* __restrict__ wsc,           // [W][R]
    unsigned short* __restrict__ Cth,        // [R][e][d] bf16
    float* __restrict__ out)
{
    __shared__ float tile[8][129];
    const int bx = blockIdx.x;
    const int r  = bx >> 4;
    const int d0 = (bx & 15) << 3;
    const int t  = threadIdx.x;
    if (bx == 0 && t == 0) out[0] = 0.0f;

    const int e  = t & 127;     // lanes consecutive in e -> coalesced reads
    const int dl = t >> 7;      // 0..1

    float acc[4] = {0.f, 0.f, 0.f, 0.f};
    for (int w = 0; w < WBAS; ++w) {
        float s = wsc[w * RCLS + r];
#pragma unroll
        for (int dd = 0; dd < 4; ++dd)
            acc[dd] += s * rel_embeds[w * 16384 + (d0 + dd * 2 + dl) * 128 + e];
    }
#pragma unroll
    for (int dd = 0; dd < 4; ++dd) tile[dd * 2 + dl][e] = acc[dd];
    __syncthreads();

    if (t < 128) {          // thread t -> output column e=t, all 8 d of the band
        unsigned short h[8];
#pragma unroll
        for (int j = 0; j < 8; ++j) h[j] = f2bf(tile[j][t]);
        size_t base = (size_t)r * 16384 + (size_t)t * 128 + d0;   // 16B aligned
        *(ushort4*)(Cth + base)     = make_ushort4(h[0], h[1], h[2], h[3]);
        *(ushort4*)(Cth + base + 4) = make_ushort4(h[4], h[5], h[6], h[7]);
    }
}

// ---- main fused kernel: 4 waves; wave w = 64 rows x cols [32w, 32w+32) ----
__global__ __launch_bounds__(256, 4) void bilinear_mfma_kernel(
    const float* __restrict__ e1g,           // [N, D]
    const float* __restrict__ e2g,           // [N, D]
    const unsigned short* __restrict__ Cth,  // [R, 128, 128] bf16
    const int*   __restrict__ rels,
    float* __restrict__ out,                 // [1 + N]
    float inv_n)
{
    __shared__ __align__(16) unsigned short s_hi[BN][SA];
    __shared__ float s_logit[BN][RCLS];

    const int tid  = threadIdx.x;
    const int n0   = blockIdx.x * BN;
    const int lane = tid & 63;
    const int w    = tid >> 6;      // wave id -> col band [32w, 32w+32)
    const int l15  = lane & 15;
    const int q    = lane >> 4;

    for (int i = tid; i < BN * RCLS; i += 256) ((float*)s_logit)[i] = 0.0f;

    // e2 in C-fragment layout: e2r[mt][nt][i] = e2[n0+16mt+4q+i][32w+16nt+l15]
    float e2r[4][2][4];
#pragma unroll
    for (int mt = 0; mt < 4; ++mt)
#pragma unroll
        for (int i = 0; i < 4; ++i) {
            const float* p = e2g + (size_t)(n0 + 16 * mt + 4 * q + i) * DDIM + 32 * w + l15;
            e2r[mt][0][i] = p[0];
            e2r[mt][1][i] = p[16];
        }

    // stage e1 -> bf16 in LDS (64 rows x 32 float4)
#pragma unroll
    for (int it = 0; it < 8; ++it) {
        int idx = it * 256 + tid;
        int row = idx >> 5, c4 = idx & 31;
        float4 v = ((const float4*)(e1g + (size_t)(n0 + row) * DDIM))[c4];
        *(ushort4*)&s_hi[row][c4 * 4] =
            make_ushort4(f2bf(v.x), f2bf(v.y), f2bf(v.z), f2bf(v.w));
    }
    __syncthreads();

    const int bofs0 = (32 * w + l15) * DDIM + q * 8;   // cols [32w, 32w+16)
    const int bofs1 = bofs0 + 16 * DDIM;               // cols [32w+16, 32w+32)

#pragma unroll
    for (int r = 0; r < RCLS; ++r) {
        f32x4 acc[4][2];
#pragma unroll
        for (int mt = 0; mt < 4; ++mt)
#pragma unroll
            for (int nt = 0; nt < 2; ++nt) {
                f32x4 z = {0.0f, 0.0f, 0.0f, 0.0f};
                acc[mt][nt] = z;
            }

        const unsigned short* bh = Cth + r * 16384;

#pragma unroll
        for (int k4 = 0; k4 < 4; ++k4) {
            bf16x8 b0 = *(const bf16x8*)(bh + bofs0 + k4 * 32);
            bf16x8 b1 = *(const bf16x8*)(bh + bofs1 + k4 * 32);
            bf16x8 ah[4];
#pragma unroll
            for (int mt = 0; mt < 4; ++mt)
                ah[mt] = *(const bf16x8*)&s_hi[16 * mt + l15][k4 * 32 + q * 8];
#pragma unroll
            for (int mt = 0; mt < 4; ++mt) {
                acc[mt][0] = __builtin_amdgcn_mfma_f32_16x16x32_bf16(ah[mt], b0, acc[mt][0], 0, 0, 0);
                acc[mt][1] = __builtin_amdgcn_mfma_f32_16x16x32_bf16(ah[mt], b1, acc[mt][1], 0, 0, 0);
            }
        }

        // contract with e2; reduce over the 16 l15-lanes; atomic into shared logits
#pragma unroll
        for (int mt = 0; mt < 4; ++mt)
#pragma unroll
            for (int i = 0; i < 4; ++i) {
                float p = acc[mt][0][i] * e2r[mt][0][i] + acc[mt][1][i] * e2r[mt][1][i];
                p += __shfl_xor(p, 1);
                p += __shfl_xor(p, 2);
                p += __shfl_xor(p, 4);
                p += __shfl_xor(p, 8);
                if (l15 == 0)
                    atomicAdd(&s_logit[16 * mt + 4 * q + i][r], p);
            }
    }
    __syncthreads();

    // epilogue: one thread per row
    if (tid < BN) {
        float l[RCLS];
#pragma unroll
        for (int r = 0; r < RCLS; ++r) l[r] = s_logit[tid][r];
        float mx = l[0];
#pragma unroll
        for (int r = 1; r < RCLS; ++r) mx = fmaxf(mx, l[r]);
        float e[RCLS], se = 0.0f;
#pragma unroll
        for (int r = 0; r < RCLS; ++r) { e[r] = __expf(l[r] - mx); se += e[r]; }
        float inv_se = 1.0f / se;
        float pred = 0.0f;
#pragma unroll
        for (int r = 0; r < RCLS; ++r) pred += (float)(r + 1) * e[r] * inv_se;
        out[1 + n0 + tid] = pred;

        int rel = rels[n0 + tid];
        float lossc = -(l[rel] - mx - logf(se)) * inv_n;
#pragma unroll
        for (int m = 1; m <= 32; m <<= 1) lossc += __shfl_xor(lossc, m);
        if (lane == 0) atomicAdd(out, lossc);
    }
}

extern "C" void kernel_launch(void* const* d_in, const int* in_sizes, int n_in,
                              void* d_out, int out_size, void* d_ws, size_t ws_size,
                              hipStream_t stream) {
    const float* e1   = (const float*)d_in[0];
    const float* e2   = (const float*)d_in[1];
    const float* rele = (const float*)d_in[2];
    const float* wsc  = (const float*)d_in[3];
    const int*   rels = (const int*)d_in[4];
    float* out = (float*)d_out;

    unsigned short* Cth = (unsigned short*)d_ws;             // 163840 B

    prep_kernel<<<80, 256, 0, stream>>>(rele, wsc, Cth, out);
    bilinear_mfma_kernel<<<NTOT / BN, 256, 0, stream>>>(
        e1, e2, Cth, rels, out, 1.0f / (float)NTOT);
}

// Round 8
// 204.211 us; speedup vs baseline: 1.3500x; 1.3500x over previous
//
#include <hip/hip_runtime.h>
#include <stdint.h>

// Problem: N=131072, D=128, W=16, R=5
//   logit[n,r] = e1[n]^T C_r e2[n],  C_r = sum_w weight[w,r] * M_w
//   out[0] = -mean(log_softmax(logit)[n, rels[n]]),  out[1..N] = expected rating
//
// R8: 1-term bf16 (absmax 1.14 < 3.12, verified R7) with the spill fixed:
//   - __launch_bounds__(256,3): the measured no-spill config (R3/R5: WRITE=640B;
//     (256,4) spilled 25-78MB in R6/R7 -> HBM-bound on scratch)
//   - r-loop pinned with #pragma unroll 1: bounds B-load hoisting to one
//     r-iteration (max 8 B-fragments in flight)
//   - SA=144 retained (0 bank conflicts measured in R6/R7)

#define NTOT 131072
#define DDIM 128
#define WBAS 16
#define RCLS 5
#define BN   64
#define SA   144     // LDS row stride (bf16); 288 B rows: conflict-free b128

typedef __attribute__((ext_vector_type(8))) short bf16x8;
typedef __attribute__((ext_vector_type(4))) float f32x4;

__device__ __forceinline__ unsigned short f2bf(float x) {
    union { float f; unsigned u; } v; v.f = x;
    unsigned u = v.u + 0x7FFFu + ((v.u >> 16) & 1u);
    return (unsigned short)(u >> 16);
}

// ---- prep: coalesced read (lanes along e), LDS transpose, bf16 ----
// grid = 80 blocks: r = bx>>4 (5), d-band d0 = (bx&15)*8 (16)
__global__ __launch_bounds__(256) void prep_kernel(
    const float* __restrict__ rel_embeds,    // [W][d][e]
    const float* __restrict__ wsc,           // [W][R]
    unsigned short* __restrict__ Cth,        // [R][e][d] bf16
    float* __restrict__ out)
{
    __shared__ float tile[8][129];
    const int bx = blockIdx.x;
    const int r  = bx >> 4;
    const int d0 = (bx & 15) << 3;
    const int t  = threadIdx.x;
    if (bx == 0 && t == 0) out[0] = 0.0f;

    const int e  = t & 127;     // lanes consecutive in e -> coalesced reads
    const int dl = t >> 7;      // 0..1

    float acc[4] = {0.f, 0.f, 0.f, 0.f};
    for (int w = 0; w < WBAS; ++w) {
        float s = wsc[w * RCLS + r];
#pragma unroll
        for (int dd = 0; dd < 4; ++dd)
            acc[dd] += s * rel_embeds[w * 16384 + (d0 + dd * 2 + dl) * 128 + e];
    }
#pragma unroll
    for (int dd = 0; dd < 4; ++dd) tile[dd * 2 + dl][e] = acc[dd];
    __syncthreads();

    if (t < 128) {          // thread t -> output column e=t, all 8 d of the band
        unsigned short h[8];
#pragma unroll
        for (int j = 0; j < 8; ++j) h[j] = f2bf(tile[j][t]);
        size_t base = (size_t)r * 16384 + (size_t)t * 128 + d0;   // 16B aligned
        *(ushort4*)(Cth + base)     = make_ushort4(h[0], h[1], h[2], h[3]);
        *(ushort4*)(Cth + base + 4) = make_ushort4(h[4], h[5], h[6], h[7]);
    }
}

// ---- main fused kernel: 4 waves; wave w = 64 rows x cols [32w, 32w+32) ----
__global__ __launch_bounds__(256, 3) void bilinear_mfma_kernel(
    const float* __restrict__ e1g,           // [N, D]
    const float* __restrict__ e2g,           // [N, D]
    const unsigned short* __restrict__ Cth,  // [R, 128, 128] bf16
    const int*   __restrict__ rels,
    float* __restrict__ out,                 // [1 + N]
    float inv_n)
{
    __shared__ __align__(16) unsigned short s_hi[BN][SA];
    __shared__ float s_logit[BN][RCLS];

    const int tid  = threadIdx.x;
    const int n0   = blockIdx.x * BN;
    const int lane = tid & 63;
    const int w    = tid >> 6;      // wave id -> col band [32w, 32w+32)
    const int l15  = lane & 15;
    const int q    = lane >> 4;

    for (int i = tid; i < BN * RCLS; i += 256) ((float*)s_logit)[i] = 0.0f;

    // e2 in C-fragment layout: e2r[mt][nt][i] = e2[n0+16mt+4q+i][32w+16nt+l15]
    float e2r[4][2][4];
#pragma unroll
    for (int mt = 0; mt < 4; ++mt)
#pragma unroll
        for (int i = 0; i < 4; ++i) {
            const float* p = e2g + (size_t)(n0 + 16 * mt + 4 * q + i) * DDIM + 32 * w + l15;
            e2r[mt][0][i] = p[0];
            e2r[mt][1][i] = p[16];
        }

    // stage e1 -> bf16 in LDS (64 rows x 32 float4)
#pragma unroll
    for (int it = 0; it < 8; ++it) {
        int idx = it * 256 + tid;
        int row = idx >> 5, c4 = idx & 31;
        float4 v = ((const float4*)(e1g + (size_t)(n0 + row) * DDIM))[c4];
        *(ushort4*)&s_hi[row][c4 * 4] =
            make_ushort4(f2bf(v.x), f2bf(v.y), f2bf(v.z), f2bf(v.w));
    }
    __syncthreads();

    const int bofs0 = (32 * w + l15) * DDIM + q * 8;   // cols [32w, 32w+16)
    const int bofs1 = bofs0 + 16 * DDIM;               // cols [32w+16, 32w+32)

    const unsigned short* bh = Cth;

#pragma unroll 1
    for (int r = 0; r < RCLS; ++r) {
        f32x4 acc[4][2];
#pragma unroll
        for (int mt = 0; mt < 4; ++mt)
#pragma unroll
            for (int nt = 0; nt < 2; ++nt) {
                f32x4 z = {0.0f, 0.0f, 0.0f, 0.0f};
                acc[mt][nt] = z;
            }

#pragma unroll
        for (int k4 = 0; k4 < 4; ++k4) {
            bf16x8 b0 = *(const bf16x8*)(bh + bofs0 + k4 * 32);
            bf16x8 b1 = *(const bf16x8*)(bh + bofs1 + k4 * 32);
            bf16x8 ah[4];
#pragma unroll
            for (int mt = 0; mt < 4; ++mt)
                ah[mt] = *(const bf16x8*)&s_hi[16 * mt + l15][k4 * 32 + q * 8];
#pragma unroll
            for (int mt = 0; mt < 4; ++mt) {
                acc[mt][0] = __builtin_amdgcn_mfma_f32_16x16x32_bf16(ah[mt], b0, acc[mt][0], 0, 0, 0);
                acc[mt][1] = __builtin_amdgcn_mfma_f32_16x16x32_bf16(ah[mt], b1, acc[mt][1], 0, 0, 0);
            }
        }

        // contract with e2; reduce over the 16 l15-lanes; atomic into shared logits
#pragma unroll
        for (int mt = 0; mt < 4; ++mt)
#pragma unroll
            for (int i = 0; i < 4; ++i) {
                float p = acc[mt][0][i] * e2r[mt][0][i] + acc[mt][1][i] * e2r[mt][1][i];
                p += __shfl_xor(p, 1);
                p += __shfl_xor(p, 2);
                p += __shfl_xor(p, 4);
                p += __shfl_xor(p, 8);
                if (l15 == 0)
                    atomicAdd(&s_logit[16 * mt + 4 * q + i][r], p);
            }

        bh += 16384;
    }
    __syncthreads();

    // epilogue: one thread per row
    if (tid < BN) {
        float l[RCLS];
#pragma unroll
        for (int r = 0; r < RCLS; ++r) l[r] = s_logit[tid][r];
        float mx = l[0];
#pragma unroll
        for (int r = 1; r < RCLS; ++r) mx = fmaxf(mx, l[r]);
        float e[RCLS], se = 0.0f;
#pragma unroll
        for (int r = 0; r < RCLS; ++r) { e[r] = __expf(l[r] - mx); se += e[r]; }
        float inv_se = 1.0f / se;
        float pred = 0.0f;
#pragma unroll
        for (int r = 0; r < RCLS; ++r) pred += (float)(r + 1) * e[r] * inv_se;
        out[1 + n0 + tid] = pred;

        int rel = rels[n0 + tid];
        float lossc = -(l[rel] - mx - logf(se)) * inv_n;
#pragma unroll
        for (int m = 1; m <= 32; m <<= 1) lossc += __shfl_xor(lossc, m);
        if (lane == 0) atomicAdd(out, lossc);
    }
}

extern "C" void kernel_launch(void* const* d_in, const int* in_sizes, int n_in,
                              void* d_out, int out_size, void* d_ws, size_t ws_size,
                              hipStream_t stream) {
    const float* e1   = (const float*)d_in[0];
    const float* e2   = (const float*)d_in[1];
    const float* rele = (const float*)d_in[2];
    const float* wsc  = (const float*)d_in[3];
    const int*   rels = (const int*)d_in[4];
    float* out = (float*)d_out;

    unsigned short* Cth = (unsigned short*)d_ws;             // 163840 B

    prep_kernel<<<80, 256, 0, stream>>>(rele, wsc, Cth, out);
    bilinear_mfma_kernel<<<NTOT / BN, 256, 0, stream>>>(
        e1, e2, Cth, rels, out, 1.0f / (float)NTOT);
}